// Round 8
// baseline (78.719 us; speedup 1.0000x reference)
//
#include <hip/hip_runtime.h>

#define NB 256
#define NP 512
#define NE 256
#define NH 128
#define PW 16              // p-rows per wave (wave-autonomous tile)

typedef __attribute__((ext_vector_type(8))) short bf16x8;
typedef __attribute__((ext_vector_type(4))) short s16x4;
typedef __attribute__((ext_vector_type(4))) float f32x4;

__device__ __forceinline__ short f2bf(float f) {
  union { float f; unsigned u; } v; v.f = f;
  unsigned r = v.u + 0x7fffu + ((v.u >> 16) & 1u);   // RNE
  return (short)(r >> 16);
}
__device__ __forceinline__ float bf2f(short s) {
  union { unsigned u; float f; } v;
  v.u = ((unsigned)(unsigned short)s) << 16;
  return v.f;
}
// tanh(x) = 1 - 2/(exp2(2*log2e*x)+1)
__device__ __forceinline__ float fast_tanh(float x) {
  float u = __builtin_amdgcn_exp2f(x * 2.8853900817779268f);
  return 1.0f - 2.0f * __builtin_amdgcn_rcpf(u + 1.0f);
}

// ---- prologue: w1 fp32 -> bf16 (64 KB, L2-hot for the main kernel) ----
__global__ void pathattn_w1cvt(const float* __restrict__ w1,
                               short* __restrict__ w1b) {
  const int i = blockIdx.x * 256 + threadIdx.x;
  w1b[i] = f2bf(w1[i]);
}

union SMem {
  short xtile[4][PW * NE];   // 4 wave-private 8 KB tiles (XOR-swizzled)
  float pool[4][NE];         // epilogue partials (alias; used after barrier)
};

// ---- main: one wave owns 16 p-rows end-to-end; zero barriers in main work ----
__global__ __launch_bounds__(256, 2) void pathattn_main(
    const float* __restrict__ x, const short* __restrict__ w1b,
    const float* __restrict__ w2, float* __restrict__ wsPool,
    float* __restrict__ wsZ) {
  __shared__ SMem sm;
  __shared__ float zsh[4];

  const int tid  = threadIdx.x;
  const int lane = tid & 63;
  const int wid  = tid >> 6;            // 0..3
  const int n15  = lane & 15;
  const int l4   = lane >> 4;           // 0..3
  const int b     = blockIdx.x >> 3;
  const int slice = blockIdx.x & 7;     // 8 p-slices of 64
  const int p0    = slice * 64 + wid * PW;   // wave's 16 p-rows
  const float* xb = x + (size_t)b * NP * NE;
  short* myt = &sm.xtile[wid][0];

  // ---- stage wave's 16x256 fp32 rows -> bf16 LDS; ALL 16 row-loads in
  // flight (single HBM latency exposure), perfectly coalesced (1 KB/instr).
  // Swizzle: short col ^= (row&7)<<3. ----
  {
    const float* src = xb + (size_t)p0 * NE + lane * 4;
    f32x4 r[PW];
    #pragma unroll
    for (int i = 0; i < PW; ++i)
      r[i] = *(const f32x4*)(src + (size_t)i * NE);
    #pragma unroll
    for (int i = 0; i < PW; ++i) {
      s16x4 v;
      v[0] = f2bf(r[i][0]); v[1] = f2bf(r[i][1]);
      v[2] = f2bf(r[i][2]); v[3] = f2bf(r[i][3]);
      *(s16x4*)(myt + i * NE + ((lane * 4) ^ ((i & 7) << 3))) = v;
    }
  }

  // ---- score MFMAs: D[h][p] = sum_k w1[h][k]*x[p][k]; 128h x 16p/wave ----
  f32x4 acc[8];
  #pragma unroll
  for (int ht = 0; ht < 8; ++ht) acc[ht] = (f32x4){0.f,0.f,0.f,0.f};

  #pragma unroll
  for (int kt = 0; kt < 8; ++kt) {
    const int kbase = kt * 32 + l4 * 8;
    // B-frag from private LDS (swizzled): lane's p-row = n15
    bf16x8 bv = *(const bf16x8*)(myt + n15 * NE + (kbase ^ ((n15 & 7) << 3)));
    // A-frags from L2/L1-hot bf16 w1
    bf16x8 av[8];
    #pragma unroll
    for (int ht = 0; ht < 8; ++ht)
      av[ht] = *(const bf16x8*)(w1b + (ht * 16 + n15) * NE + kbase);
    #pragma unroll
    for (int ht = 0; ht < 8; ++ht)
      acc[ht] = __builtin_amdgcn_mfma_f32_16x16x32_bf16(av[ht], bv, acc[ht], 0, 0, 0);
  }

  // ---- tanh * w2, reduce over h (local + 2 shuffles), exp ----
  // D layout: col(p)=lane&15, row(h)=ht*16 + l4*4 + r
  float s0 = 0.f;
  #pragma unroll
  for (int ht = 0; ht < 8; ++ht) {
    f32x4 wv = *(const f32x4*)(w2 + ht * 16 + l4 * 4);
    #pragma unroll
    for (int r = 0; r < 4; ++r)
      s0 += fast_tanh(acc[ht][r]) * wv[r];
  }
  s0 += __shfl_xor(s0, 16, 64);
  s0 += __shfl_xor(s0, 32, 64);
  // no max-subtraction needed: |s| <= ||w2||_1 <= 12.8
  const float e0 = __builtin_amdgcn_exp2f(s0 * 1.4426950408889634f);
  float zacc = e0;                      // 4x replicated across l4 groups

  // ---- pooling from private LDS: row-broadcast b64 reads, 2-way max ----
  f32x4 pacc = {0.f, 0.f, 0.f, 0.f};
  #pragma unroll
  for (int pp = 0; pp < PW; ++pp) {
    const float ep = __shfl(e0, pp, 64);
    s16x4 v = *(const s16x4*)(myt + pp * NE + ((lane * 4) ^ ((pp & 7) << 3)));
    pacc[0] += ep * bf2f(v[0]); pacc[1] += ep * bf2f(v[1]);
    pacc[2] += ep * bf2f(v[2]); pacc[3] += ep * bf2f(v[3]);
  }

  // ---- Z reduce (wave): sum over 64 lanes = 4x the true Z ----
  #pragma unroll
  for (int m = 1; m <= 32; m <<= 1) zacc += __shfl_xor(zacc, m, 64);
  if (lane == 0) zsh[wid] = zacc * 0.25f;

  // ---- epilogue: barrier, then reuse tile LDS for cross-wave pool reduce ----
  __syncthreads();                       // all tile reads done; safe to alias
  *(f32x4*)(&sm.pool[wid][lane * 4]) = pacc;
  __syncthreads();
  float v = sm.pool[0][tid] + sm.pool[1][tid] + sm.pool[2][tid] + sm.pool[3][tid];
  wsPool[(size_t)blockIdx.x * NE + tid] = v;
  if (tid == 0)
    wsZ[blockIdx.x] = zsh[0] + zsh[1] + zsh[2] + zsh[3];
}

// ---- combine the eight P-slices and normalize ----
__global__ void pathattn_combine(const float* __restrict__ wsPool,
                                 const float* __restrict__ wsZ,
                                 float* __restrict__ out) {
  const int b = blockIdx.x, e = threadIdx.x;
  float v = 0.f, z = 0.f;
  #pragma unroll
  for (int q = 0; q < 8; ++q) {
    v += wsPool[(size_t)(8 * b + q) * NE + e];
    z += wsZ[8 * b + q];
  }
  out[(size_t)b * NE + e] = v / z;
}

extern "C" void kernel_launch(void* const* d_in, const int* in_sizes, int n_in,
                              void* d_out, int out_size, void* d_ws, size_t ws_size,
                              hipStream_t stream) {
  (void)in_sizes; (void)n_in; (void)out_size; (void)ws_size;
  const float* x  = (const float*)d_in[0];
  const float* w1 = (const float*)d_in[1];
  const float* w2 = (const float*)d_in[2];
  float* out = (float*)d_out;
  short* w1b    = (short*)d_ws;                    // [128*256] bf16 (64 KB)
  float* wsPool = (float*)((char*)d_ws + 65536);   // [2048][256] f32
  float* wsZ    = wsPool + 2048 * NE;              // [2048] f32
  pathattn_w1cvt<<<NH * NE / 256, 256, 0, stream>>>(w1, w1b);
  pathattn_main<<<8 * NB, 256, 0, stream>>>(x, w1b, w2, wsPool, wsZ);
  pathattn_combine<<<NB, NE, 0, stream>>>(wsPool, wsZ, out);
}

// Round 9
// 50.547 us; speedup vs baseline: 1.5573x; 1.5573x over previous
//
#include <hip/hip_runtime.h>

#define NB 256
#define NP 512
#define NE 256
#define NH 128
#define PT 32              // pool rows per tile
#define HALF 256           // pool rows per block (P split across 2 blocks)
#define NT (HALF / PT)     // 8 tiles per block

typedef __attribute__((ext_vector_type(8))) short bf16x8;
typedef __attribute__((ext_vector_type(4))) float f32x4;

__device__ __forceinline__ short f2bf(float f) {
  union { float f; unsigned u; } v; v.f = f;
  unsigned r = v.u + 0x7fffu + ((v.u >> 16) & 1u);   // RNE
  return (short)(r >> 16);
}
// tanh(x) = 1 - 2/(exp2(2*log2e*x)+1)
__device__ __forceinline__ float fast_tanh(float x) {
  float u = __builtin_amdgcn_exp2f(x * 2.8853900817779268f);
  return 1.0f - 2.0f * __builtin_amdgcn_rcpf(u + 1.0f);
}

// ---- prologue: w1 fp32 -> bf16 (64 KB, L2-hot for the main kernel) ----
__global__ void pathattn_w1cvt(const float* __restrict__ w1,
                               short* __restrict__ w1b) {
  const int i = blockIdx.x * 256 + threadIdx.x;
  w1b[i] = f2bf(w1[i]);
}

// ---- main: 8-wave block, fp32 LDS tiles staged by global_load_lds with
// source-side XOR swizzle (LDS linear). Wave w owns h-rows [16w,16w+16). ----
__global__ __launch_bounds__(512, 2) void pathattn_main(
    const float* __restrict__ x, const short* __restrict__ w1b,
    const float* __restrict__ w2, float* __restrict__ wsPool,
    float* __restrict__ wsZ) {
  __shared__ float xs[2][PT * NE];     // 2 x 32 KB fp32 tiles (slot-swizzled)
  __shared__ float sp[PT][12];         // score partials [p][wave], 16B-aligned rows
  __shared__ float pool[8][NE];        // per-wave pooled partials
  __shared__ float zsh[8];

  const int tid  = threadIdx.x;
  const int lane = tid & 63;
  const int wid  = tid >> 6;            // 0..7
  const int n15  = lane & 15;
  const int l4   = lane >> 4;           // 0..3
  const int b    = blockIdx.x >> 1;
  const int half = blockIdx.x & 1;
  const float* xb = x + (size_t)b * NP * NE + (size_t)half * HALF * NE;

  // ---- A-fragments: wave's 16 w1-rows, bf16, L2-hot (32 VGPR total) ----
  bf16x8 afrag[8];
  #pragma unroll
  for (int kt = 0; kt < 8; ++kt)
    afrag[kt] = *(const bf16x8*)(w1b + (wid * 16 + n15) * NE + kt * 32 + l4 * 8);
  const f32x4 w2v = *(const f32x4*)(w2 + wid * 16 + l4 * 4);

  // ---- staging: global_load_lds w=16, LDS linear, global source swizzled.
  // LDS 16B-slot cs of row r holds global chunk cs ^ (r&7). ----
  auto stage = [&](int t) {
    float* dst = xs[t & 1];
    const float* gb = xb + (size_t)t * PT * NE;
    #pragma unroll
    for (int j = 0; j < 4; ++j) {
      const int r = wid * 4 + j;
      const float* g = gb + (size_t)r * NE + ((lane ^ (r & 7)) << 2);
      __builtin_amdgcn_global_load_lds(
          (const __attribute__((address_space(1))) unsigned int*)g,
          (__attribute__((address_space(3))) unsigned int*)(dst + r * NE),
          16, 0, 0);
    }
  };

  // ---- MFMA phase: D[h][p] = sum_k w1[h][k]*x[p][k]; wave: 16h x 32p ----
  auto mfma_phase = [&](int t) {
    const float* xt = xs[t & 1];
    f32x4 acc0 = {0.f,0.f,0.f,0.f}, acc1 = {0.f,0.f,0.f,0.f};
    const int m7 = n15 & 7;
    #pragma unroll
    for (int kt = 0; kt < 8; ++kt) {
      const int s0 = kt * 8 + l4 * 2;   // 16B-slot of k-range start
      #pragma unroll
      for (int pg = 0; pg < 2; ++pg) {
        const float* rowp = xt + (pg * 16 + n15) * NE;
        f32x4 lo = *(const f32x4*)(rowp + (((s0)     ^ m7) << 2));
        f32x4 hi = *(const f32x4*)(rowp + (((s0 + 1) ^ m7) << 2));
        bf16x8 bv;
        bv[0]=f2bf(lo[0]); bv[1]=f2bf(lo[1]); bv[2]=f2bf(lo[2]); bv[3]=f2bf(lo[3]);
        bv[4]=f2bf(hi[0]); bv[5]=f2bf(hi[1]); bv[6]=f2bf(hi[2]); bv[7]=f2bf(hi[3]);
        if (pg == 0)
          acc0 = __builtin_amdgcn_mfma_f32_16x16x32_bf16(afrag[kt], bv, acc0, 0, 0, 0);
        else
          acc1 = __builtin_amdgcn_mfma_f32_16x16x32_bf16(afrag[kt], bv, acc1, 0, 0, 0);
      }
    }
    // D layout: col(p)=n15, row(h)=wid*16 + l4*4 + r
    float s0v = 0.f, s1v = 0.f;
    #pragma unroll
    for (int r = 0; r < 4; ++r) {
      s0v += fast_tanh(acc0[r]) * w2v[r];
      s1v += fast_tanh(acc1[r]) * w2v[r];
    }
    s0v += __shfl_xor(s0v, 16, 64); s0v += __shfl_xor(s0v, 32, 64);
    s1v += __shfl_xor(s1v, 16, 64); s1v += __shfl_xor(s1v, 32, 64);
    if (l4 == 0) {
      sp[n15][wid]      = s0v;
      sp[16 + n15][wid] = s1v;
    }
  };

  // ---- exp + pooling: wave handles rows [wid*4, wid*4+4) of the tile ----
  f32x4 pacc = {0.f, 0.f, 0.f, 0.f};
  float zacc = 0.f;
  auto exp_pool = [&](int t) {
    const float* xt = xs[t & 1];
    #pragma unroll
    for (int j = 0; j < 4; ++j) {
      const int r = wid * 4 + j;
      f32x4 a = *(const f32x4*)(&sp[r][0]);   // broadcast reads (free)
      f32x4 c = *(const f32x4*)(&sp[r][4]);
      float s = (a[0]+a[1]+a[2]+a[3]) + (c[0]+c[1]+c[2]+c[3]);
      // no max-subtraction: |s| <= ||w2||_1 <= 12.8
      float e = __builtin_amdgcn_exp2f(s * 1.4426950408889634f);
      zacc += e;                               // identical across lanes
      f32x4 v = *(const f32x4*)(xt + r * NE + ((lane ^ (r & 7)) << 2));
      pacc[0] += e * v[0]; pacc[1] += e * v[1];
      pacc[2] += e * v[2]; pacc[3] += e * v[3];
    }
  };

  // ---- pipeline: double buffer, prefetch before compute, 2 barriers/tile ----
  stage(0);
  __syncthreads();                       // drains stage(0)
  for (int t = 0; t < NT; ++t) {
    if (t + 1 < NT) stage(t + 1);        // in flight across MFMA phase
    mfma_phase(t);
    __syncthreads();                     // B1: sp visible (drains prefetch)
    exp_pool(t);
    __syncthreads();                     // B2: xs[t&1] reads done
  }

  // ---- epilogue ----
  if (lane == 0) zsh[wid] = zacc;        // zacc uniform across wave
  *(f32x4*)(&pool[wid][lane << 2]) = pacc;   // wave covers e = lane*4..+3
  __syncthreads();
  if (tid < NE) {
    float v = 0.f;
    #pragma unroll
    for (int w = 0; w < 8; ++w) v += pool[w][tid];
    wsPool[(size_t)blockIdx.x * NE + tid] = v;
  }
  if (tid == 0) {
    float z = 0.f;
    #pragma unroll
    for (int w = 0; w < 8; ++w) z += zsh[w];
    wsZ[blockIdx.x] = z;
  }
}

// ---- combine the two P-halves and normalize ----
__global__ void pathattn_combine(const float* __restrict__ wsPool,
                                 const float* __restrict__ wsZ,
                                 float* __restrict__ out) {
  const int b = blockIdx.x, e = threadIdx.x;
  float v = wsPool[(size_t)(2*b) * NE + e] + wsPool[(size_t)(2*b+1) * NE + e];
  float z = wsZ[2*b] + wsZ[2*b+1];
  out[(size_t)b * NE + e] = v / z;
}

extern "C" void kernel_launch(void* const* d_in, const int* in_sizes, int n_in,
                              void* d_out, int out_size, void* d_ws, size_t ws_size,
                              hipStream_t stream) {
  (void)in_sizes; (void)n_in; (void)out_size; (void)ws_size;
  const float* x  = (const float*)d_in[0];
  const float* w1 = (const float*)d_in[1];
  const float* w2 = (const float*)d_in[2];
  float* out = (float*)d_out;
  short* w1b    = (short*)d_ws;                    // [128*256] bf16 (64 KB)
  float* wsPool = (float*)((char*)d_ws + 65536);   // [512][256] f32
  float* wsZ    = wsPool + 512 * NE;               // [512] f32
  pathattn_w1cvt<<<NH * NE / 256, 256, 0, stream>>>(w1, w1b);
  pathattn_main<<<2 * NB, 512, 0, stream>>>(x, w1b, w2, wsPool, wsZ);
  pathattn_combine<<<NB, NE, 0, stream>>>(wsPool, wsZ, out);
}